// Round 1
// baseline (971.238 us; speedup 1.0000x reference)
//
#include <hip/hip_runtime.h>

#define NN 100000
#define NE 1600000
#define FIN 256
#define HID 64
#define NCLS 10
#define EPSF 0.3f

// ---------- setup kernels ----------

// w1T[c*64+k] = w1[k*256+c]  (64KB, run once per call)
__global__ void k_wt(const float* __restrict__ w1, float* __restrict__ w1T) {
    int t = blockIdx.x * 256 + threadIdx.x;
    if (t < HID * FIN) {
        int c = t >> 6, k = t & 63;
        w1T[t] = w1[k * FIN + c];
    }
}

__global__ void k_deg(const int* __restrict__ ei, int* __restrict__ deg) {
    int e = blockIdx.x * 256 + threadIdx.x;
    if (e < NE) atomicAdd(&deg[ei[NE + e]], 1);
}

__global__ void k_dis(const int* __restrict__ deg, float* __restrict__ dis) {
    int i = blockIdx.x * 256 + threadIdx.x;
    if (i < NN) {
        int d = deg[i];
        dis[i] = (d > 0) ? (1.0f / sqrtf((float)d)) : 0.0f;
    }
}

// 3-kernel exclusive scan of deg -> rp (row_ptr), chunk = 1024
__global__ void k_scan1(const int* __restrict__ deg, int* __restrict__ rp, int* __restrict__ bsum) {
    __shared__ int s[1024];
    int i = blockIdx.x * 1024 + threadIdx.x;
    int v = (i < NN) ? deg[i] : 0;
    s[threadIdx.x] = v;
    __syncthreads();
    for (int off = 1; off < 1024; off <<= 1) {
        int t = (threadIdx.x >= off) ? s[threadIdx.x - off] : 0;
        __syncthreads();
        s[threadIdx.x] += t;
        __syncthreads();
    }
    if (i < NN) rp[i] = s[threadIdx.x] - v;            // exclusive
    if (threadIdx.x == 1023) bsum[blockIdx.x] = s[1023]; // block total
}

__global__ void k_scan2(int* __restrict__ bsum, int nb) {
    __shared__ int s[128];
    int v = (threadIdx.x < nb) ? bsum[threadIdx.x] : 0;
    s[threadIdx.x] = v;
    __syncthreads();
    for (int off = 1; off < 128; off <<= 1) {
        int t = (threadIdx.x >= off) ? s[threadIdx.x - off] : 0;
        __syncthreads();
        s[threadIdx.x] += t;
        __syncthreads();
    }
    if (threadIdx.x < nb) bsum[threadIdx.x] = s[threadIdx.x] - v;
}

__global__ void k_scan3(int* __restrict__ rp, const int* __restrict__ bsum) {
    int i = blockIdx.x * 1024 + threadIdx.x;
    if (i < NN) rp[i] += bsum[blockIdx.x];
    if (i == 0) rp[NN] = NE;
}

__global__ void k_fill(const int* __restrict__ ei, const int* __restrict__ rp,
                       int* __restrict__ cursor, int* __restrict__ csr_src, int* __restrict__ csr_dst) {
    int e = blockIdx.x * 256 + threadIdx.x;
    if (e < NE) {
        int s = ei[e], d = ei[NE + e];
        int pos = rp[d] + atomicAdd(&cursor[d], 1);
        csr_src[pos] = s;
        csr_dst[pos] = d;
    }
}

// ---------- compute kernels ----------

// h = relu(x @ w1.T + b1). lanes = hid k, wave handles 8 nodes, block = 32 nodes.
__global__ __launch_bounds__(256) void k_gemm1(const float* __restrict__ x, const float* __restrict__ w1T,
                                               const float* __restrict__ b1, float* __restrict__ h) {
    int lane = threadIdx.x & 63;
    int wave = threadIdx.x >> 6;
    int n0 = blockIdx.x * 32 + wave * 8;
    float acc[8];
    float bk = b1[lane];
#pragma unroll
    for (int r = 0; r < 8; r++) acc[r] = bk;
    for (int c0 = 0; c0 < FIN; c0 += 4) {
        float wa = w1T[(c0 + 0) * HID + lane];  // coalesced across lanes
        float wb = w1T[(c0 + 1) * HID + lane];
        float wc = w1T[(c0 + 2) * HID + lane];
        float wd = w1T[(c0 + 3) * HID + lane];
#pragma unroll
        for (int r = 0; r < 8; r++) {
            float4 xv = *reinterpret_cast<const float4*>(&x[(size_t)(n0 + r) * FIN + c0]); // wave-uniform, broadcast
            acc[r] = fmaf(xv.x, wa, acc[r]);
            acc[r] = fmaf(xv.y, wb, acc[r]);
            acc[r] = fmaf(xv.z, wc, acc[r]);
            acc[r] = fmaf(xv.w, wd, acc[r]);
        }
    }
#pragma unroll
    for (int r = 0; r < 8; r++) h[(size_t)(n0 + r) * HID + lane] = fmaxf(acc[r], 0.0f);
}

// per-node al = h.att_l, ar = h.att_r (wave per node, butterfly reduce)
__global__ void k_alar(const float* __restrict__ h, const float* __restrict__ att_l, const float* __restrict__ att_r,
                       const float* __restrict__ dis, float2* __restrict__ aldis, float* __restrict__ ar, int layer) {
    int lane = threadIdx.x & 63;
    int i = blockIdx.x * 4 + (threadIdx.x >> 6);
    if (i >= NN) return;
    float hv = h[(size_t)i * HID + lane];
    float p = hv * att_l[layer * HID + lane];
    float q = hv * att_r[layer * HID + lane];
#pragma unroll
    for (int m = 1; m < 64; m <<= 1) {
        p += __shfl_xor(p, m, 64);
        q += __shfl_xor(q, m, 64);
    }
    if (lane == 0) {
        aldis[i] = make_float2(p, dis[i]);  // pack al with dis -> single 8B gather later
        ar[i] = q;
    }
}

// per-edge coefficient: tanh(al[src]+ar[dst]) * dis[src]*dis[dst], in CSR order
__global__ void k_coef(const int* __restrict__ csr_src, const int* __restrict__ csr_dst,
                       const float2* __restrict__ aldis, const float* __restrict__ ar,
                       const float* __restrict__ dis, float* __restrict__ coef) {
    int e = blockIdx.x * 256 + threadIdx.x;
    if (e < NE) {
        int j = csr_src[e], i = csr_dst[e];
        float2 ad = aldis[j];
        coef[e] = tanhf(ad.x + ar[i]) * (ad.y * dis[i]);
    }
}

// wave per node: h_out[i] = EPS*raw[i] + sum_e coef[e] * h_in[src[e]]
__global__ __launch_bounds__(256) void k_agg(const float* __restrict__ h_in, const float* __restrict__ raw,
                                             const int* __restrict__ rp, const int* __restrict__ csr_src,
                                             const float* __restrict__ coef, float* __restrict__ h_out) {
    int lane = threadIdx.x & 63;
    int i = blockIdx.x * 4 + (threadIdx.x >> 6);
    if (i >= NN) return;
    float acc = EPSF * raw[(size_t)i * HID + lane];
    int e0 = rp[i], e1 = rp[i + 1];
    for (int e = e0; e < e1; ++e) {
        int j = csr_src[e];             // wave-uniform
        float c = coef[e];              // wave-uniform
        acc += h_in[(size_t)j * HID + lane] * c;  // coalesced 256B row gather
    }
    h_out[(size_t)i * HID + lane] = acc;
}

// logits + log_softmax, wave per node
__global__ void k_logits(const float* __restrict__ h, const float* __restrict__ w2, const float* __restrict__ b2,
                         float* __restrict__ out) {
    int lane = threadIdx.x & 63;
    int i = blockIdx.x * 4 + (threadIdx.x >> 6);
    if (i >= NN) return;
    float hv = h[(size_t)i * HID + lane];
    float lg[NCLS];
#pragma unroll
    for (int c = 0; c < NCLS; c++) {
        float p = hv * w2[c * HID + lane];
#pragma unroll
        for (int m = 1; m < 64; m <<= 1) p += __shfl_xor(p, m, 64);
        lg[c] = p + b2[c];
    }
    float mx = lg[0];
#pragma unroll
    for (int c = 1; c < NCLS; c++) mx = fmaxf(mx, lg[c]);
    float ssum = 0.0f;
#pragma unroll
    for (int c = 0; c < NCLS; c++) ssum += expf(lg[c] - mx);
    float r = mx + logf(ssum);
    if (lane < NCLS) {
        float v = 0.0f;
#pragma unroll
        for (int c = 0; c < NCLS; c++)
            if (lane == c) v = lg[c];
        out[(size_t)i * NCLS + lane] = v - r;
    }
}

// ---------- launch ----------

extern "C" void kernel_launch(void* const* d_in, const int* in_sizes, int n_in,
                              void* d_out, int out_size, void* d_ws, size_t ws_size,
                              hipStream_t stream) {
    const float* x     = (const float*)d_in[0];
    const int*   ei    = (const int*)d_in[1];
    const float* w1    = (const float*)d_in[2];
    const float* b1    = (const float*)d_in[3];
    const float* w2    = (const float*)d_in[4];
    const float* b2    = (const float*)d_in[5];
    const float* att_l = (const float*)d_in[6];
    const float* att_r = (const float*)d_in[7];
    float* out = (float*)d_out;

    char* ws = (char*)d_ws;
    size_t off = 0;
    auto take = [&](size_t bytes) -> void* {
        void* p = ws + off;
        off += (bytes + 255) & ~(size_t)255;
        return p;
    };
    int*    deg     = (int*)take((size_t)NN * 4);
    int*    cursor  = (int*)take((size_t)NN * 4);
    int*    rp      = (int*)take((size_t)(NN + 1) * 4);
    int*    bsum    = (int*)take(128 * 4);
    float*  dis     = (float*)take((size_t)NN * 4);
    float*  ar      = (float*)take((size_t)NN * 4);
    float2* aldis   = (float2*)take((size_t)NN * 8);
    float*  w1T     = (float*)take((size_t)HID * FIN * 4);
    int*    csr_src = (int*)take((size_t)NE * 4);
    int*    csr_dst = (int*)take((size_t)NE * 4);
    float*  coef    = (float*)take((size_t)NE * 4);
    float*  hA      = (float*)take((size_t)NN * HID * 4);
    float*  hB      = (float*)take((size_t)NN * HID * 4);
    float*  hC      = (float*)take((size_t)NN * HID * 4);

    hipMemsetAsync(deg, 0, (size_t)NN * 4, stream);
    hipMemsetAsync(cursor, 0, (size_t)NN * 4, stream);

    const int EB = (NE + 255) / 256;
    const int NB = (NN + 255) / 256;
    const int SB = (NN + 1023) / 1024;  // 98

    k_wt<<<64, 256, 0, stream>>>(w1, w1T);
    k_deg<<<EB, 256, 0, stream>>>(ei, deg);
    k_dis<<<NB, 256, 0, stream>>>(deg, dis);
    k_scan1<<<SB, 1024, 0, stream>>>(deg, rp, bsum);
    k_scan2<<<1, 128, 0, stream>>>(bsum, SB);
    k_scan3<<<SB, 1024, 0, stream>>>(rp, bsum);
    k_fill<<<EB, 256, 0, stream>>>(ei, rp, cursor, csr_src, csr_dst);

    k_gemm1<<<NN / 32, 256, 0, stream>>>(x, w1T, b1, hA);

    // layer 0: in hA, raw hA -> hB
    k_alar<<<NN / 4, 256, 0, stream>>>(hA, att_l, att_r, dis, aldis, ar, 0);
    k_coef<<<EB, 256, 0, stream>>>(csr_src, csr_dst, aldis, ar, dis, coef);
    k_agg<<<NN / 4, 256, 0, stream>>>(hA, hA, rp, csr_src, coef, hB);

    // layer 1: in hB, raw hA -> hC
    k_alar<<<NN / 4, 256, 0, stream>>>(hB, att_l, att_r, dis, aldis, ar, 1);
    k_coef<<<EB, 256, 0, stream>>>(csr_src, csr_dst, aldis, ar, dis, coef);
    k_agg<<<NN / 4, 256, 0, stream>>>(hB, hA, rp, csr_src, coef, hC);

    k_logits<<<NN / 4, 256, 0, stream>>>(hC, w2, b2, out);
}

// Round 2
// 820.381 us; speedup vs baseline: 1.1839x; 1.1839x over previous
//
#include <hip/hip_runtime.h>

#define NN 100000
#define NE 1600000
#define FIN 256
#define HID 64
#define NCLS 10
#define EPSF 0.3f

// ---------- setup kernels ----------

// w1T[k*64+h] = w1[h*256+k]  (64KB, run once per call)
__global__ void k_wt(const float* __restrict__ w1, float* __restrict__ w1T) {
    int t = blockIdx.x * 256 + threadIdx.x;
    if (t < HID * FIN) {
        int h = t >> 6, k = t & 63;  // dummy split; recompute properly below
    }
    // proper: t indexes w1T flat [k][h]
    if (t < HID * FIN) {
        int k = t >> 6;      // 0..255
        int h = t & 63;      // 0..63
        w1T[t] = w1[h * FIN + k];
    }
}

__global__ void k_deg(const int* __restrict__ ei, int* __restrict__ deg) {
    int e = blockIdx.x * 256 + threadIdx.x;
    if (e < NE) atomicAdd(&deg[ei[NE + e]], 1);
}

__global__ void k_dis(const int* __restrict__ deg, float* __restrict__ dis) {
    int i = blockIdx.x * 256 + threadIdx.x;
    if (i < NN) {
        int d = deg[i];
        dis[i] = (d > 0) ? (1.0f / sqrtf((float)d)) : 0.0f;
    }
}

// 3-kernel exclusive scan of deg -> rp (row_ptr), chunk = 1024
__global__ void k_scan1(const int* __restrict__ deg, int* __restrict__ rp, int* __restrict__ bsum) {
    __shared__ int s[1024];
    int i = blockIdx.x * 1024 + threadIdx.x;
    int v = (i < NN) ? deg[i] : 0;
    s[threadIdx.x] = v;
    __syncthreads();
    for (int off = 1; off < 1024; off <<= 1) {
        int t = (threadIdx.x >= off) ? s[threadIdx.x - off] : 0;
        __syncthreads();
        s[threadIdx.x] += t;
        __syncthreads();
    }
    if (i < NN) rp[i] = s[threadIdx.x] - v;              // exclusive
    if (threadIdx.x == 1023) bsum[blockIdx.x] = s[1023]; // block total
}

__global__ void k_scan2(int* __restrict__ bsum, int nb) {
    __shared__ int s[128];
    int v = (threadIdx.x < nb) ? bsum[threadIdx.x] : 0;
    s[threadIdx.x] = v;
    __syncthreads();
    for (int off = 1; off < 128; off <<= 1) {
        int t = (threadIdx.x >= off) ? s[threadIdx.x - off] : 0;
        __syncthreads();
        s[threadIdx.x] += t;
        __syncthreads();
    }
    if (threadIdx.x < nb) bsum[threadIdx.x] = s[threadIdx.x] - v;
}

__global__ void k_scan3(int* __restrict__ rp, const int* __restrict__ bsum) {
    int i = blockIdx.x * 1024 + threadIdx.x;
    if (i < NN) rp[i] += bsum[blockIdx.x];
    if (i == 0) rp[NN] = NE;
}

__global__ void k_fill(const int* __restrict__ ei, const int* __restrict__ rp,
                       int* __restrict__ cursor, int2* __restrict__ csr) {
    int e = blockIdx.x * 256 + threadIdx.x;
    if (e < NE) {
        int s = ei[e], d = ei[NE + e];
        int pos = rp[d] + atomicAdd(&cursor[d], 1);
        csr[pos] = make_int2(s, d);   // single 8B scatter
    }
}

// ---------- compute kernels ----------

// h = relu(x @ w1.T + b1). lane = node, acc over all 64 hid.
// x row per lane via scattered float4 (line reused 4 steps); w1T rows are
// wave-uniform addresses -> scalar loads (off the VMEM critical path).
__global__ __launch_bounds__(64) void k_gemm1(const float* __restrict__ x, const float* __restrict__ w1T,
                                              const float* __restrict__ b1, float* __restrict__ h) {
    int n = blockIdx.x * 64 + threadIdx.x;
    if (n >= NN) return;
    float acc[HID];
#pragma unroll
    for (int j = 0; j < HID; j++) acc[j] = b1[j];   // uniform -> s_load
    const float4* __restrict__ xr = reinterpret_cast<const float4*>(x + (size_t)n * FIN);
    const float4* __restrict__ wr = reinterpret_cast<const float4*>(w1T);
    for (int k4 = 0; k4 < FIN / 4; k4++) {
        float4 xv = xr[k4];
        const float* xf = &xv.x;
#pragma unroll
        for (int kk = 0; kk < 4; kk++) {
            float xs = xf[kk];
            const float4* wrow = wr + (size_t)(k4 * 4 + kk) * (HID / 4);  // wave-uniform
#pragma unroll
            for (int hq = 0; hq < HID / 4; hq++) {
                float4 wq = wrow[hq];
                acc[hq * 4 + 0] = fmaf(xs, wq.x, acc[hq * 4 + 0]);
                acc[hq * 4 + 1] = fmaf(xs, wq.y, acc[hq * 4 + 1]);
                acc[hq * 4 + 2] = fmaf(xs, wq.z, acc[hq * 4 + 2]);
                acc[hq * 4 + 3] = fmaf(xs, wq.w, acc[hq * 4 + 3]);
            }
        }
    }
    float4* __restrict__ ho = reinterpret_cast<float4*>(h + (size_t)n * HID);
#pragma unroll
    for (int hq = 0; hq < HID / 4; hq++) {
        float4 v;
        v.x = fmaxf(acc[hq * 4 + 0], 0.0f);
        v.y = fmaxf(acc[hq * 4 + 1], 0.0f);
        v.z = fmaxf(acc[hq * 4 + 2], 0.0f);
        v.w = fmaxf(acc[hq * 4 + 3], 0.0f);
        ho[hq] = v;
    }
}

// per-node al = h.att_l, ar = h.att_r (wave per node, butterfly reduce)
// packs: aldis[i] = {al, dis}, ardis[i] = {ar, dis}
__global__ void k_alar(const float* __restrict__ h, const float* __restrict__ att_l, const float* __restrict__ att_r,
                       const float* __restrict__ dis, float2* __restrict__ aldis, float2* __restrict__ ardis,
                       int layer) {
    int lane = threadIdx.x & 63;
    int i = blockIdx.x * 4 + (threadIdx.x >> 6);
    if (i >= NN) return;
    float hv = h[(size_t)i * HID + lane];
    float p = hv * att_l[layer * HID + lane];
    float q = hv * att_r[layer * HID + lane];
#pragma unroll
    for (int m = 1; m < 64; m <<= 1) {
        p += __shfl_xor(p, m, 64);
        q += __shfl_xor(q, m, 64);
    }
    if (lane == 0) {
        float ds = dis[i];
        aldis[i] = make_float2(p, ds);
        ardis[i] = make_float2(q, ds);
    }
}

// per-edge coefficient: tanh(al[src]+ar[dst]) * dis[src]*dis[dst], in CSR order
__global__ void k_coef(const int2* __restrict__ csr, const float2* __restrict__ aldis,
                       const float2* __restrict__ ardis, float* __restrict__ coef) {
    int e = blockIdx.x * 256 + threadIdx.x;
    if (e < NE) {
        int2 sd = csr[e];
        float2 al = aldis[sd.x];   // random 8B gather (L2-resident, 800KB)
        float2 ar = ardis[sd.y];   // dst sorted in CSR order -> quasi-sequential
        coef[e] = tanhf(al.x + ar.x) * (al.y * ar.y);
    }
}

// wave per node: h_out[i] = EPS*raw[i] + sum_e coef[e] * h_in[src[e]]
__global__ __launch_bounds__(256) void k_agg(const float* __restrict__ h_in, const float* __restrict__ raw,
                                             const int* __restrict__ rp, const int2* __restrict__ csr,
                                             const float* __restrict__ coef, float* __restrict__ h_out) {
    int lane = threadIdx.x & 63;
    int i = blockIdx.x * 4 + (threadIdx.x >> 6);
    if (i >= NN) return;
    float acc = EPSF * raw[(size_t)i * HID + lane];
    int e0 = rp[i], e1 = rp[i + 1];
    for (int e = e0; e < e1; ++e) {
        int j = csr[e].x;               // wave-uniform scalar load
        float c = coef[e];              // wave-uniform scalar load
        acc += h_in[(size_t)j * HID + lane] * c;  // coalesced 256B row gather
    }
    h_out[(size_t)i * HID + lane] = acc;
}

// logits + log_softmax, wave per node
__global__ void k_logits(const float* __restrict__ h, const float* __restrict__ w2, const float* __restrict__ b2,
                         float* __restrict__ out) {
    int lane = threadIdx.x & 63;
    int i = blockIdx.x * 4 + (threadIdx.x >> 6);
    if (i >= NN) return;
    float hv = h[(size_t)i * HID + lane];
    float lg[NCLS];
#pragma unroll
    for (int c = 0; c < NCLS; c++) {
        float p = hv * w2[c * HID + lane];
#pragma unroll
        for (int m = 1; m < 64; m <<= 1) p += __shfl_xor(p, m, 64);
        lg[c] = p + b2[c];
    }
    float mx = lg[0];
#pragma unroll
    for (int c = 1; c < NCLS; c++) mx = fmaxf(mx, lg[c]);
    float ssum = 0.0f;
#pragma unroll
    for (int c = 0; c < NCLS; c++) ssum += expf(lg[c] - mx);
    float r = mx + logf(ssum);
    if (lane < NCLS) {
        float v = 0.0f;
#pragma unroll
        for (int c = 0; c < NCLS; c++)
            if (lane == c) v = lg[c];
        out[(size_t)i * NCLS + lane] = v - r;
    }
}

// ---------- launch ----------

extern "C" void kernel_launch(void* const* d_in, const int* in_sizes, int n_in,
                              void* d_out, int out_size, void* d_ws, size_t ws_size,
                              hipStream_t stream) {
    const float* x     = (const float*)d_in[0];
    const int*   ei    = (const int*)d_in[1];
    const float* w1    = (const float*)d_in[2];
    const float* b1    = (const float*)d_in[3];
    const float* w2    = (const float*)d_in[4];
    const float* b2    = (const float*)d_in[5];
    const float* att_l = (const float*)d_in[6];
    const float* att_r = (const float*)d_in[7];
    float* out = (float*)d_out;

    char* ws = (char*)d_ws;
    size_t off = 0;
    auto take = [&](size_t bytes) -> void* {
        void* p = ws + off;
        off += (bytes + 255) & ~(size_t)255;
        return p;
    };
    int*    deg     = (int*)take((size_t)NN * 4);
    int*    cursor  = (int*)take((size_t)NN * 4);
    int*    rp      = (int*)take((size_t)(NN + 1) * 4);
    int*    bsum    = (int*)take(128 * 4);
    float*  dis     = (float*)take((size_t)NN * 4);
    float2* aldis   = (float2*)take((size_t)NN * 8);
    float2* ardis   = (float2*)take((size_t)NN * 8);
    float*  w1T     = (float*)take((size_t)HID * FIN * 4);
    int2*   csr     = (int2*)take((size_t)NE * 8);
    float*  coef    = (float*)take((size_t)NE * 4);
    float*  hA      = (float*)take((size_t)NN * HID * 4);
    float*  hB      = (float*)take((size_t)NN * HID * 4);
    float*  hC      = (float*)take((size_t)NN * HID * 4);

    hipMemsetAsync(deg, 0, (size_t)NN * 4, stream);
    hipMemsetAsync(cursor, 0, (size_t)NN * 4, stream);

    const int EB = (NE + 255) / 256;
    const int NB = (NN + 255) / 256;
    const int SB = (NN + 1023) / 1024;  // 98

    k_wt<<<64, 256, 0, stream>>>(w1, w1T);
    k_deg<<<EB, 256, 0, stream>>>(ei, deg);
    k_dis<<<NB, 256, 0, stream>>>(deg, dis);
    k_scan1<<<SB, 1024, 0, stream>>>(deg, rp, bsum);
    k_scan2<<<1, 128, 0, stream>>>(bsum, SB);
    k_scan3<<<SB, 1024, 0, stream>>>(rp, bsum);
    k_fill<<<EB, 256, 0, stream>>>(ei, rp, cursor, csr);

    k_gemm1<<<(NN + 63) / 64, 64, 0, stream>>>(x, w1T, b1, hA);

    // layer 0: in hA, raw hA -> hB
    k_alar<<<NN / 4, 256, 0, stream>>>(hA, att_l, att_r, dis, aldis, ardis, 0);
    k_coef<<<EB, 256, 0, stream>>>(csr, aldis, ardis, coef);
    k_agg<<<NN / 4, 256, 0, stream>>>(hA, hA, rp, csr, coef, hB);

    // layer 1: in hB, raw hA -> hC
    k_alar<<<NN / 4, 256, 0, stream>>>(hB, att_l, att_r, dis, aldis, ardis, 1);
    k_coef<<<EB, 256, 0, stream>>>(csr, aldis, ardis, coef);
    k_agg<<<NN / 4, 256, 0, stream>>>(hB, hA, rp, csr, coef, hC);

    k_logits<<<NN / 4, 256, 0, stream>>>(hC, w2, b2, out);
}

// Round 4
// 593.953 us; speedup vs baseline: 1.6352x; 1.3812x over previous
//
#include <hip/hip_runtime.h>

#define NN 100000
#define NE 1600000
#define FIN 256
#define HID 64
#define NCLS 10
#define EPSF 0.3f

// ---------- setup kernels ----------

// w1T[k*64+h] = w1[h*256+k]  (64KB, run once per call)
__global__ void k_wt(const float* __restrict__ w1, float* __restrict__ w1T) {
    int t = blockIdx.x * 256 + threadIdx.x;
    if (t < HID * FIN) {
        int k = t >> 6;      // 0..255
        int h = t & 63;      // 0..63
        w1T[t] = w1[h * FIN + k];
    }
}

__global__ void k_deg(const int* __restrict__ ei, int* __restrict__ deg) {
    int e = blockIdx.x * 256 + threadIdx.x;
    if (e < NE) atomicAdd(&deg[ei[NE + e]], 1);
}

__global__ void k_dis(const int* __restrict__ deg, float* __restrict__ dis) {
    int i = blockIdx.x * 256 + threadIdx.x;
    if (i < NN) {
        int d = deg[i];
        dis[i] = (d > 0) ? (1.0f / sqrtf((float)d)) : 0.0f;
    }
}

// 3-kernel exclusive scan of deg -> rp (row_ptr), chunk = 1024
__global__ void k_scan1(const int* __restrict__ deg, int* __restrict__ rp, int* __restrict__ bsum) {
    __shared__ int s[1024];
    int i = blockIdx.x * 1024 + threadIdx.x;
    int v = (i < NN) ? deg[i] : 0;
    s[threadIdx.x] = v;
    __syncthreads();
    for (int off = 1; off < 1024; off <<= 1) {
        int t = (threadIdx.x >= off) ? s[threadIdx.x - off] : 0;
        __syncthreads();
        s[threadIdx.x] += t;
        __syncthreads();
    }
    if (i < NN) rp[i] = s[threadIdx.x] - v;              // exclusive
    if (threadIdx.x == 1023) bsum[blockIdx.x] = s[1023]; // block total
}

__global__ void k_scan2(int* __restrict__ bsum, int nb) {
    __shared__ int s[128];
    int v = (threadIdx.x < nb) ? bsum[threadIdx.x] : 0;
    s[threadIdx.x] = v;
    __syncthreads();
    for (int off = 1; off < 128; off <<= 1) {
        int t = (threadIdx.x >= off) ? s[threadIdx.x - off] : 0;
        __syncthreads();
        s[threadIdx.x] += t;
        __syncthreads();
    }
    if (threadIdx.x < nb) bsum[threadIdx.x] = s[threadIdx.x] - v;
}

__global__ void k_scan3(int* __restrict__ rp, const int* __restrict__ bsum) {
    int i = blockIdx.x * 1024 + threadIdx.x;
    if (i < NN) rp[i] += bsum[blockIdx.x];
    if (i == 0) rp[NN] = NE;
}

__global__ void k_fill(const int* __restrict__ ei, const int* __restrict__ rp,
                       int* __restrict__ cursor, int2* __restrict__ csr) {
    int e = blockIdx.x * 256 + threadIdx.x;
    if (e < NE) {
        int s = ei[e], d = ei[NE + e];
        int pos = rp[d] + atomicAdd(&cursor[d], 1);
        csr[pos] = make_int2(s, d);   // single 8B scatter
    }
}

// ---------- compute kernels ----------

// h = relu(x @ w1.T + b1), lane = node, acc over all 64 hid.
// Epilogue: layer-0 attention scores al/ar (fused, h-row already in regs).
__global__ __launch_bounds__(64) void k_gemm1(const float* __restrict__ x, const float* __restrict__ w1T,
                                              const float* __restrict__ b1, const float* __restrict__ dis,
                                              const float* __restrict__ att_l0, const float* __restrict__ att_r0,
                                              float* __restrict__ h,
                                              float2* __restrict__ aldis, float2* __restrict__ ardis) {
    int n = blockIdx.x * 64 + threadIdx.x;
    if (n >= NN) return;
    float acc[HID];
#pragma unroll
    for (int j = 0; j < HID; j++) acc[j] = b1[j];   // uniform -> s_load
    const float4* __restrict__ xr = reinterpret_cast<const float4*>(x + (size_t)n * FIN);
    const float4* __restrict__ wr = reinterpret_cast<const float4*>(w1T);
    for (int k4 = 0; k4 < FIN / 4; k4++) {
        float4 xv = xr[k4];
        const float* xf = &xv.x;
#pragma unroll
        for (int kk = 0; kk < 4; kk++) {
            float xs = xf[kk];
            const float4* wrow = wr + (size_t)(k4 * 4 + kk) * (HID / 4);  // wave-uniform
#pragma unroll
            for (int hq = 0; hq < HID / 4; hq++) {
                float4 wq = wrow[hq];
                acc[hq * 4 + 0] = fmaf(xs, wq.x, acc[hq * 4 + 0]);
                acc[hq * 4 + 1] = fmaf(xs, wq.y, acc[hq * 4 + 1]);
                acc[hq * 4 + 2] = fmaf(xs, wq.z, acc[hq * 4 + 2]);
                acc[hq * 4 + 3] = fmaf(xs, wq.w, acc[hq * 4 + 3]);
            }
        }
    }
    float4* __restrict__ ho = reinterpret_cast<float4*>(h + (size_t)n * HID);
    float p = 0.0f, q = 0.0f;
#pragma unroll
    for (int hq = 0; hq < HID / 4; hq++) {
        float4 v;
        v.x = fmaxf(acc[hq * 4 + 0], 0.0f);
        v.y = fmaxf(acc[hq * 4 + 1], 0.0f);
        v.z = fmaxf(acc[hq * 4 + 2], 0.0f);
        v.w = fmaxf(acc[hq * 4 + 3], 0.0f);
        ho[hq] = v;
        // fused layer-0 scores (att uniform -> s_load)
        p = fmaf(v.x, att_l0[hq * 4 + 0], p); q = fmaf(v.x, att_r0[hq * 4 + 0], q);
        p = fmaf(v.y, att_l0[hq * 4 + 1], p); q = fmaf(v.y, att_r0[hq * 4 + 1], q);
        p = fmaf(v.z, att_l0[hq * 4 + 2], p); q = fmaf(v.z, att_r0[hq * 4 + 2], q);
        p = fmaf(v.w, att_l0[hq * 4 + 3], p); q = fmaf(v.w, att_r0[hq * 4 + 3], q);
    }
    float ds = dis[n];
    aldis[n] = make_float2(p, ds);
    ardis[n] = make_float2(q, ds);
}

// per-edge coefficient: tanh(al[src]+ar[dst]) * dis[src]*dis[dst], in CSR order
__global__ void k_coef(const int2* __restrict__ csr, const float2* __restrict__ aldis,
                       const float2* __restrict__ ardis, float* __restrict__ coef) {
    int e = blockIdx.x * 256 + threadIdx.x;
    if (e < NE) {
        int2 sd = csr[e];
        float2 al = aldis[sd.x];   // random 8B gather (800KB table, L2-resident)
        float2 ar = ardis[sd.y];   // dst in CSR order -> quasi-sequential
        coef[e] = tanhf(al.x + ar.x) * (al.y * ar.y);
    }
}

// wave per node: acc[lane] = EPS*raw + sum coef*h_in[src].
// Edge {src,coef} preloaded lane-parallel (coalesced) and broadcast via shfl;
// gathers 4-deep pipelined with independent accumulators.
// MODE 0: write h_out. MODE 1: also fused next-layer scores. MODE 2: fused logits+log_softmax, no h_out.
template <int MODE>
__global__ __launch_bounds__(256) void k_agg(const float* __restrict__ h_in, const float* __restrict__ raw,
                                             const int* __restrict__ rp, const int2* __restrict__ csr,
                                             const float* __restrict__ coef, float* __restrict__ h_out,
                                             const float* __restrict__ att_l, const float* __restrict__ att_r,
                                             const float* __restrict__ dis,
                                             float2* __restrict__ aldis, float2* __restrict__ ardis,
                                             const float* __restrict__ w2, const float* __restrict__ b2,
                                             float* __restrict__ out) {
    int lane = threadIdx.x & 63;
    int i = blockIdx.x * 4 + (threadIdx.x >> 6);
    if (i >= NN) return;
    float acc = EPSF * raw[(size_t)i * HID + lane];
    int e0 = rp[i], e1 = rp[i + 1];
    int deg = e1 - e0;
    float a0 = 0.0f, a1 = 0.0f, a2 = 0.0f, a3 = 0.0f;
    for (int base = 0; base < deg; base += 64) {
        int rem = deg - base; if (rem > 64) rem = 64;
        int j = 0; float c = 0.0f;
        if (lane < rem) {
            j = csr[e0 + base + lane].x;   // coalesced
            c = coef[e0 + base + lane];    // coalesced
        }
        int t = 0;
        for (; t + 4 <= rem; t += 4) {
            int j0 = __shfl(j, t, 64), j1 = __shfl(j, t + 1, 64);
            int j2 = __shfl(j, t + 2, 64), j3 = __shfl(j, t + 3, 64);
            float c0 = __shfl(c, t, 64), c1 = __shfl(c, t + 1, 64);
            float c2 = __shfl(c, t + 2, 64), c3 = __shfl(c, t + 3, 64);
            float h0 = h_in[(size_t)j0 * HID + lane];
            float h1 = h_in[(size_t)j1 * HID + lane];
            float h2 = h_in[(size_t)j2 * HID + lane];
            float h3 = h_in[(size_t)j3 * HID + lane];
            a0 = fmaf(h0, c0, a0);
            a1 = fmaf(h1, c1, a1);
            a2 = fmaf(h2, c2, a2);
            a3 = fmaf(h3, c3, a3);
        }
        for (; t < rem; ++t) {
            int jj = __shfl(j, t, 64);
            float cc = __shfl(c, t, 64);
            a0 = fmaf(h_in[(size_t)jj * HID + lane], cc, a0);
        }
    }
    acc += (a0 + a1) + (a2 + a3);

    if (MODE == 2) {
        // fused logits + log_softmax
        float lg[NCLS];
#pragma unroll
        for (int cc = 0; cc < NCLS; cc++) {
            float p = acc * w2[cc * HID + lane];
#pragma unroll
            for (int m = 1; m < 64; m <<= 1) p += __shfl_xor(p, m, 64);
            lg[cc] = p + b2[cc];
        }
        float mx = lg[0];
#pragma unroll
        for (int cc = 1; cc < NCLS; cc++) mx = fmaxf(mx, lg[cc]);
        float ssum = 0.0f;
#pragma unroll
        for (int cc = 0; cc < NCLS; cc++) ssum += expf(lg[cc] - mx);
        float r = mx + logf(ssum);
        if (lane < NCLS) {
            float v = 0.0f;
#pragma unroll
            for (int cc = 0; cc < NCLS; cc++)
                if (lane == cc) v = lg[cc];
            out[(size_t)i * NCLS + lane] = v - r;
        }
    } else {
        h_out[(size_t)i * HID + lane] = acc;
        if (MODE == 1) {
            // fused next-layer scores
            float p = acc * att_l[lane];
            float q = acc * att_r[lane];
#pragma unroll
            for (int m = 1; m < 64; m <<= 1) {
                p += __shfl_xor(p, m, 64);
                q += __shfl_xor(q, m, 64);
            }
            if (lane == 0) {
                float ds = dis[i];
                aldis[i] = make_float2(p, ds);
                ardis[i] = make_float2(q, ds);
            }
        }
    }
}

// ---------- launch ----------

extern "C" void kernel_launch(void* const* d_in, const int* in_sizes, int n_in,
                              void* d_out, int out_size, void* d_ws, size_t ws_size,
                              hipStream_t stream) {
    const float* x     = (const float*)d_in[0];
    const int*   ei    = (const int*)d_in[1];
    const float* w1    = (const float*)d_in[2];
    const float* b1    = (const float*)d_in[3];
    const float* w2    = (const float*)d_in[4];
    const float* b2    = (const float*)d_in[5];
    const float* att_l = (const float*)d_in[6];
    const float* att_r = (const float*)d_in[7];
    float* out = (float*)d_out;

    char* ws = (char*)d_ws;
    size_t off = 0;
    auto take = [&](size_t bytes) -> void* {
        void* p = ws + off;
        off += (bytes + 255) & ~(size_t)255;
        return p;
    };
    int*    deg     = (int*)take((size_t)NN * 4);
    int*    cursor  = (int*)take((size_t)NN * 4);
    int*    rp      = (int*)take((size_t)(NN + 1) * 4);
    int*    bsum    = (int*)take(128 * 4);
    float*  dis     = (float*)take((size_t)NN * 4);
    float2* aldis   = (float2*)take((size_t)NN * 8);
    float2* ardis   = (float2*)take((size_t)NN * 8);
    float*  w1T     = (float*)take((size_t)HID * FIN * 4);
    int2*   csr     = (int2*)take((size_t)NE * 8);
    float*  coef    = (float*)take((size_t)NE * 4);
    float*  hA      = (float*)take((size_t)NN * HID * 4);
    float*  hB      = (float*)take((size_t)NN * HID * 4);

    hipMemsetAsync(deg, 0, (size_t)NN * 4, stream);
    hipMemsetAsync(cursor, 0, (size_t)NN * 4, stream);

    const int EB = (NE + 255) / 256;
    const int NB = (NN + 255) / 256;
    const int SB = (NN + 1023) / 1024;  // 98

    k_wt<<<64, 256, 0, stream>>>(w1, w1T);
    k_deg<<<EB, 256, 0, stream>>>(ei, deg);
    k_dis<<<NB, 256, 0, stream>>>(deg, dis);
    k_scan1<<<SB, 1024, 0, stream>>>(deg, rp, bsum);
    k_scan2<<<1, 128, 0, stream>>>(bsum, SB);
    k_scan3<<<SB, 1024, 0, stream>>>(rp, bsum);
    k_fill<<<EB, 256, 0, stream>>>(ei, rp, cursor, csr);

    // lin1 + ReLU + fused layer-0 scores
    k_gemm1<<<(NN + 63) / 64, 64, 0, stream>>>(x, w1T, b1, dis, att_l, att_r, hA, aldis, ardis);

    // layer 0: in hA, raw hA -> hB, fused layer-1 scores
    k_coef<<<EB, 256, 0, stream>>>(csr, aldis, ardis, coef);
    k_agg<1><<<NN / 4, 256, 0, stream>>>(hA, hA, rp, csr, coef, hB,
                                         att_l + HID, att_r + HID, dis, aldis, ardis,
                                         nullptr, nullptr, nullptr);

    // layer 1: in hB, raw hA -> fused logits/log_softmax -> out
    k_coef<<<EB, 256, 0, stream>>>(csr, aldis, ardis, coef);
    k_agg<2><<<NN / 4, 256, 0, stream>>>(hB, hA, rp, csr, coef, nullptr,
                                         nullptr, nullptr, nullptr, nullptr, nullptr,
                                         w2, b2, out);
}

// Round 5
// 557.045 us; speedup vs baseline: 1.7436x; 1.0663x over previous
//
#include <hip/hip_runtime.h>

#define NN 100000
#define NE 1600000
#define FIN 256
#define HID 64
#define NCLS 10
#define EPSF 0.3f

// ---------- setup kernels ----------

// w1T[k*64+h] = w1[h*256+k]  (64KB, run once per call)
__global__ void k_wt(const float* __restrict__ w1, float* __restrict__ w1T) {
    int t = blockIdx.x * 256 + threadIdx.x;
    if (t < HID * FIN) {
        int k = t >> 6;      // 0..255
        int h = t & 63;      // 0..63
        w1T[t] = w1[h * FIN + k];
    }
}

__global__ void k_deg(const int* __restrict__ ei, int* __restrict__ deg) {
    int e = blockIdx.x * 256 + threadIdx.x;
    if (e < NE) atomicAdd(&deg[ei[NE + e]], 1);
}

__global__ void k_dis(const int* __restrict__ deg, float* __restrict__ dis) {
    int i = blockIdx.x * 256 + threadIdx.x;
    if (i < NN) {
        int d = deg[i];
        dis[i] = (d > 0) ? (1.0f / sqrtf((float)d)) : 0.0f;
    }
}

// 3-kernel exclusive scan of deg -> rp (row_ptr), chunk = 1024
__global__ void k_scan1(const int* __restrict__ deg, int* __restrict__ rp, int* __restrict__ bsum) {
    __shared__ int s[1024];
    int i = blockIdx.x * 1024 + threadIdx.x;
    int v = (i < NN) ? deg[i] : 0;
    s[threadIdx.x] = v;
    __syncthreads();
    for (int off = 1; off < 1024; off <<= 1) {
        int t = (threadIdx.x >= off) ? s[threadIdx.x - off] : 0;
        __syncthreads();
        s[threadIdx.x] += t;
        __syncthreads();
    }
    if (i < NN) rp[i] = s[threadIdx.x] - v;              // exclusive
    if (threadIdx.x == 1023) bsum[blockIdx.x] = s[1023]; // block total
}

__global__ void k_scan2(int* __restrict__ bsum, int nb) {
    __shared__ int s[128];
    int v = (threadIdx.x < nb) ? bsum[threadIdx.x] : 0;
    s[threadIdx.x] = v;
    __syncthreads();
    for (int off = 1; off < 128; off <<= 1) {
        int t = (threadIdx.x >= off) ? s[threadIdx.x - off] : 0;
        __syncthreads();
        s[threadIdx.x] += t;
        __syncthreads();
    }
    if (threadIdx.x < nb) bsum[threadIdx.x] = s[threadIdx.x] - v;
}

__global__ void k_scan3(int* __restrict__ rp, const int* __restrict__ bsum) {
    int i = blockIdx.x * 1024 + threadIdx.x;
    if (i < NN) rp[i] += bsum[blockIdx.x];
    if (i == 0) rp[NN] = NE;
}

// store src only (4B scatter, not 8B) -> halves scatter write amplification
__global__ void k_fill(const int* __restrict__ ei, const int* __restrict__ rp,
                       int* __restrict__ cursor, int* __restrict__ csr_src) {
    int e = blockIdx.x * 256 + threadIdx.x;
    if (e < NE) {
        int s = ei[e], d = ei[NE + e];
        int pos = rp[d] + atomicAdd(&cursor[d], 1);
        csr_src[pos] = s;
    }
}

// ---------- compute kernels ----------

// h = relu(x @ w1.T + b1), lane = node. w1T staged in LDS (64KB), x prefetched.
// Epilogue: layer-0 attention scores al/ar.
__global__ __launch_bounds__(256) void k_gemm1(const float* __restrict__ x, const float* __restrict__ w1T,
                                               const float* __restrict__ b1, const float* __restrict__ dis,
                                               const float* __restrict__ att_l0, const float* __restrict__ att_r0,
                                               float* __restrict__ h,
                                               float2* __restrict__ aldis, float2* __restrict__ ardis) {
    __shared__ float4 wlds[FIN * (HID / 4)];   // 4096 float4 = 64KB
    const float4* __restrict__ wr = reinterpret_cast<const float4*>(w1T);
    for (int t = threadIdx.x; t < FIN * (HID / 4); t += 256) wlds[t] = wr[t];  // coalesced
    __syncthreads();

    int n = blockIdx.x * 256 + threadIdx.x;
    bool act = (n < NN);
    int nc = act ? n : (NN - 1);
    float acc[HID];
#pragma unroll
    for (int j = 0; j < HID; j++) acc[j] = b1[j];   // uniform -> s_load
    const float4* __restrict__ xr = reinterpret_cast<const float4*>(x + (size_t)nc * FIN);

    float4 cur = xr[0];
#pragma unroll 1
    for (int k4 = 0; k4 < FIN / 4; k4++) {
        float4 nxt = make_float4(0.f, 0.f, 0.f, 0.f);
        if (k4 < FIN / 4 - 1) nxt = xr[k4 + 1];    // prefetch: independent of FMA block
        const float* xf = &cur.x;
#pragma unroll
        for (int kk = 0; kk < 4; kk++) {
            float xs = xf[kk];
            const float4* wrow = &wlds[(k4 * 4 + kk) * (HID / 4)];  // wave-uniform ds_read (broadcast)
#pragma unroll
            for (int hq = 0; hq < HID / 4; hq++) {
                float4 wq = wrow[hq];
                acc[hq * 4 + 0] = fmaf(xs, wq.x, acc[hq * 4 + 0]);
                acc[hq * 4 + 1] = fmaf(xs, wq.y, acc[hq * 4 + 1]);
                acc[hq * 4 + 2] = fmaf(xs, wq.z, acc[hq * 4 + 2]);
                acc[hq * 4 + 3] = fmaf(xs, wq.w, acc[hq * 4 + 3]);
            }
        }
        cur = nxt;
    }

    if (!act) return;
    float4* __restrict__ ho = reinterpret_cast<float4*>(h + (size_t)n * HID);
    float p = 0.0f, q = 0.0f;
#pragma unroll
    for (int hq = 0; hq < HID / 4; hq++) {
        float4 v;
        v.x = fmaxf(acc[hq * 4 + 0], 0.0f);
        v.y = fmaxf(acc[hq * 4 + 1], 0.0f);
        v.z = fmaxf(acc[hq * 4 + 2], 0.0f);
        v.w = fmaxf(acc[hq * 4 + 3], 0.0f);
        ho[hq] = v;
        p = fmaf(v.x, att_l0[hq * 4 + 0], p); q = fmaf(v.x, att_r0[hq * 4 + 0], q);
        p = fmaf(v.y, att_l0[hq * 4 + 1], p); q = fmaf(v.y, att_r0[hq * 4 + 1], q);
        p = fmaf(v.z, att_l0[hq * 4 + 2], p); q = fmaf(v.z, att_r0[hq * 4 + 2], q);
        p = fmaf(v.w, att_l0[hq * 4 + 3], p); q = fmaf(v.w, att_r0[hq * 4 + 3], q);
    }
    float ds = dis[n];
    aldis[n] = make_float2(p, ds);
    ardis[n] = make_float2(q, ds);
}

// wave per node: acc[lane] = EPS*raw + sum tanh(al_j+ar_i)*dis_j*dis_i * h_in[j].
// coef computed in-register per lane during the coalesced edge preload (dst == i).
// MODE 1: write h_out + fused next-layer scores into aldis_o/ardis_o (separate buffers!).
// MODE 2: fused logits + log_softmax, no h_out.
template <int MODE>
__global__ __launch_bounds__(256) void k_agg(const float* __restrict__ h_in, const float* __restrict__ raw,
                                             const int* __restrict__ rp, const int* __restrict__ csr_src,
                                             const float2* __restrict__ aldis_i, const float2* __restrict__ ardis_i,
                                             float* __restrict__ h_out,
                                             const float* __restrict__ att_l, const float* __restrict__ att_r,
                                             const float* __restrict__ dis,
                                             float2* __restrict__ aldis_o, float2* __restrict__ ardis_o,
                                             const float* __restrict__ w2, const float* __restrict__ b2,
                                             float* __restrict__ out) {
    int lane = threadIdx.x & 63;
    int i = blockIdx.x * 4 + (threadIdx.x >> 6);
    if (i >= NN) return;
    float2 ai = ardis_i[i];   // {ar_i, dis_i} wave-uniform
    float acc = EPSF * raw[(size_t)i * HID + lane];
    int e0 = rp[i], e1 = rp[i + 1];
    int deg = e1 - e0;
    float a0 = 0.0f, a1 = 0.0f, a2 = 0.0f, a3 = 0.0f;
    for (int base = 0; base < deg; base += 64) {
        int rem = deg - base; if (rem > 64) rem = 64;
        int j = 0; float cf = 0.0f;
        if (lane < rem) {
            j = csr_src[e0 + base + lane];           // coalesced 4B
            float2 aj = aldis_i[j];                  // random 8B gather, 64 in flight
            cf = tanhf(aj.x + ai.x) * (aj.y * ai.y); // fused coef
        }
        int t = 0;
        for (; t + 4 <= rem; t += 4) {
            int j0 = __shfl(j, t, 64), j1 = __shfl(j, t + 1, 64);
            int j2 = __shfl(j, t + 2, 64), j3 = __shfl(j, t + 3, 64);
            float c0 = __shfl(cf, t, 64), c1 = __shfl(cf, t + 1, 64);
            float c2 = __shfl(cf, t + 2, 64), c3 = __shfl(cf, t + 3, 64);
            float h0 = h_in[(size_t)j0 * HID + lane];
            float h1 = h_in[(size_t)j1 * HID + lane];
            float h2 = h_in[(size_t)j2 * HID + lane];
            float h3 = h_in[(size_t)j3 * HID + lane];
            a0 = fmaf(h0, c0, a0);
            a1 = fmaf(h1, c1, a1);
            a2 = fmaf(h2, c2, a2);
            a3 = fmaf(h3, c3, a3);
        }
        for (; t < rem; ++t) {
            int jj = __shfl(j, t, 64);
            float cc = __shfl(cf, t, 64);
            a0 = fmaf(h_in[(size_t)jj * HID + lane], cc, a0);
        }
    }
    acc += (a0 + a1) + (a2 + a3);

    if (MODE == 2) {
        float lg[NCLS];
#pragma unroll
        for (int cc = 0; cc < NCLS; cc++) {
            float p = acc * w2[cc * HID + lane];
#pragma unroll
            for (int m = 1; m < 64; m <<= 1) p += __shfl_xor(p, m, 64);
            lg[cc] = p + b2[cc];
        }
        float mx = lg[0];
#pragma unroll
        for (int cc = 1; cc < NCLS; cc++) mx = fmaxf(mx, lg[cc]);
        float ssum = 0.0f;
#pragma unroll
        for (int cc = 0; cc < NCLS; cc++) ssum += expf(lg[cc] - mx);
        float r = mx + logf(ssum);
        if (lane < NCLS) {
            float v = 0.0f;
#pragma unroll
            for (int cc = 0; cc < NCLS; cc++)
                if (lane == cc) v = lg[cc];
            out[(size_t)i * NCLS + lane] = v - r;
        }
    } else {
        h_out[(size_t)i * HID + lane] = acc;
        if (MODE == 1) {
            float p = acc * att_l[lane];
            float q = acc * att_r[lane];
#pragma unroll
            for (int m = 1; m < 64; m <<= 1) {
                p += __shfl_xor(p, m, 64);
                q += __shfl_xor(q, m, 64);
            }
            if (lane == 0) {
                float ds = dis[i];
                aldis_o[i] = make_float2(p, ds);
                ardis_o[i] = make_float2(q, ds);
            }
        }
    }
}

// ---------- launch ----------

extern "C" void kernel_launch(void* const* d_in, const int* in_sizes, int n_in,
                              void* d_out, int out_size, void* d_ws, size_t ws_size,
                              hipStream_t stream) {
    const float* x     = (const float*)d_in[0];
    const int*   ei    = (const int*)d_in[1];
    const float* w1    = (const float*)d_in[2];
    const float* b1    = (const float*)d_in[3];
    const float* w2    = (const float*)d_in[4];
    const float* b2    = (const float*)d_in[5];
    const float* att_l = (const float*)d_in[6];
    const float* att_r = (const float*)d_in[7];
    float* out = (float*)d_out;

    char* ws = (char*)d_ws;
    size_t off = 0;
    auto take = [&](size_t bytes) -> void* {
        void* p = ws + off;
        off += (bytes + 255) & ~(size_t)255;
        return p;
    };
    int*    deg     = (int*)take((size_t)NN * 4);
    int*    cursor  = (int*)take((size_t)NN * 4);
    int*    rp      = (int*)take((size_t)(NN + 1) * 4);
    int*    bsum    = (int*)take(128 * 4);
    float*  dis     = (float*)take((size_t)NN * 4);
    float2* aldisA  = (float2*)take((size_t)NN * 8);
    float2* ardisA  = (float2*)take((size_t)NN * 8);
    float2* aldisB  = (float2*)take((size_t)NN * 8);
    float2* ardisB  = (float2*)take((size_t)NN * 8);
    float*  w1T     = (float*)take((size_t)HID * FIN * 4);
    int*    csr_src = (int*)take((size_t)NE * 4);
    float*  hA      = (float*)take((size_t)NN * HID * 4);
    float*  hB      = (float*)take((size_t)NN * HID * 4);

    hipMemsetAsync(deg, 0, (size_t)NN * 4, stream);
    hipMemsetAsync(cursor, 0, (size_t)NN * 4, stream);

    const int EB = (NE + 255) / 256;
    const int NB = (NN + 255) / 256;
    const int SB = (NN + 1023) / 1024;  // 98

    k_wt<<<64, 256, 0, stream>>>(w1, w1T);
    k_deg<<<EB, 256, 0, stream>>>(ei, deg);
    k_dis<<<NB, 256, 0, stream>>>(deg, dis);
    k_scan1<<<SB, 1024, 0, stream>>>(deg, rp, bsum);
    k_scan2<<<1, 128, 0, stream>>>(bsum, SB);
    k_scan3<<<SB, 1024, 0, stream>>>(rp, bsum);
    k_fill<<<EB, 256, 0, stream>>>(ei, rp, cursor, csr_src);

    // lin1 + ReLU + fused layer-0 scores -> aldisA/ardisA
    k_gemm1<<<(NN + 255) / 256, 256, 0, stream>>>(x, w1T, b1, dis, att_l, att_r, hA, aldisA, ardisA);

    // layer 0: in hA (scores A), raw hA -> hB, fused layer-1 scores -> B buffers
    k_agg<1><<<NN / 4, 256, 0, stream>>>(hA, hA, rp, csr_src, aldisA, ardisA, hB,
                                         att_l + HID, att_r + HID, dis, aldisB, ardisB,
                                         nullptr, nullptr, nullptr);

    // layer 1: in hB (scores B), raw hA -> fused logits/log_softmax -> out
    k_agg<2><<<NN / 4, 256, 0, stream>>>(hB, hA, rp, csr_src, aldisB, ardisB, nullptr,
                                         nullptr, nullptr, nullptr, nullptr, nullptr,
                                         w2, b2, out);
}

// Round 6
// 536.854 us; speedup vs baseline: 1.8091x; 1.0376x over previous
//
#include <hip/hip_runtime.h>

#define NN 100000
#define NE 1600000
#define FIN 256
#define HID 64
#define NCLS 10
#define EPSF 0.3f

// ---------- setup kernels ----------

// w1T[k*64+h] = w1[h*256+k]  (64KB, run once per call)
__global__ void k_wt(const float* __restrict__ w1, float* __restrict__ w1T) {
    int t = blockIdx.x * 256 + threadIdx.x;
    if (t < HID * FIN) {
        int k = t >> 6;      // 0..255
        int h = t & 63;      // 0..63
        w1T[t] = w1[h * FIN + k];
    }
}

__global__ void k_deg(const int* __restrict__ ei, int* __restrict__ deg) {
    int e = blockIdx.x * 256 + threadIdx.x;
    if (e < NE) atomicAdd(&deg[ei[NE + e]], 1);
}

__global__ void k_dis(const int* __restrict__ deg, float* __restrict__ dis) {
    int i = blockIdx.x * 256 + threadIdx.x;
    if (i < NN) {
        int d = deg[i];
        dis[i] = (d > 0) ? (1.0f / sqrtf((float)d)) : 0.0f;
    }
}

// 3-kernel exclusive scan of deg -> rp (row_ptr), chunk = 1024
__global__ void k_scan1(const int* __restrict__ deg, int* __restrict__ rp, int* __restrict__ bsum) {
    __shared__ int s[1024];
    int i = blockIdx.x * 1024 + threadIdx.x;
    int v = (i < NN) ? deg[i] : 0;
    s[threadIdx.x] = v;
    __syncthreads();
    for (int off = 1; off < 1024; off <<= 1) {
        int t = (threadIdx.x >= off) ? s[threadIdx.x - off] : 0;
        __syncthreads();
        s[threadIdx.x] += t;
        __syncthreads();
    }
    if (i < NN) rp[i] = s[threadIdx.x] - v;              // exclusive
    if (threadIdx.x == 1023) bsum[blockIdx.x] = s[1023]; // block total
}

__global__ void k_scan2(int* __restrict__ bsum, int nb) {
    __shared__ int s[128];
    int v = (threadIdx.x < nb) ? bsum[threadIdx.x] : 0;
    s[threadIdx.x] = v;
    __syncthreads();
    for (int off = 1; off < 128; off <<= 1) {
        int t = (threadIdx.x >= off) ? s[threadIdx.x - off] : 0;
        __syncthreads();
        s[threadIdx.x] += t;
        __syncthreads();
    }
    if (threadIdx.x < nb) bsum[threadIdx.x] = s[threadIdx.x] - v;
}

__global__ void k_scan3(int* __restrict__ rp, const int* __restrict__ bsum) {
    int i = blockIdx.x * 1024 + threadIdx.x;
    if (i < NN) rp[i] += bsum[blockIdx.x];
    if (i == 0) rp[NN] = NE;
}

// store src only (4B scatter) -> halves scatter write amplification
__global__ void k_fill(const int* __restrict__ ei, const int* __restrict__ rp,
                       int* __restrict__ cursor, int* __restrict__ csr_src) {
    int e = blockIdx.x * 256 + threadIdx.x;
    if (e < NE) {
        int s = ei[e], d = ei[NE + e];
        int pos = rp[d] + atomicAdd(&cursor[d], 1);
        csr_src[pos] = s;
    }
}

// ---------- compute kernels ----------

// h = relu(x @ w1.T + b1), lane = node. w1T staged in LDS (64KB), x prefetched.
// Epilogue: layer-0 attention scores al/ar.
__global__ __launch_bounds__(256) void k_gemm1(const float* __restrict__ x, const float* __restrict__ w1T,
                                               const float* __restrict__ b1, const float* __restrict__ dis,
                                               const float* __restrict__ att_l0, const float* __restrict__ att_r0,
                                               float* __restrict__ h,
                                               float2* __restrict__ aldis, float2* __restrict__ ardis) {
    __shared__ float4 wlds[FIN * (HID / 4)];   // 4096 float4 = 64KB
    const float4* __restrict__ wr = reinterpret_cast<const float4*>(w1T);
    for (int t = threadIdx.x; t < FIN * (HID / 4); t += 256) wlds[t] = wr[t];  // coalesced
    __syncthreads();

    int n = blockIdx.x * 256 + threadIdx.x;
    bool act = (n < NN);
    int nc = act ? n : (NN - 1);
    float acc[HID];
#pragma unroll
    for (int j = 0; j < HID; j++) acc[j] = b1[j];   // uniform -> s_load
    const float4* __restrict__ xr = reinterpret_cast<const float4*>(x + (size_t)nc * FIN);

    float4 cur = xr[0];
#pragma unroll 1
    for (int k4 = 0; k4 < FIN / 4; k4++) {
        float4 nxt = make_float4(0.f, 0.f, 0.f, 0.f);
        if (k4 < FIN / 4 - 1) nxt = xr[k4 + 1];    // prefetch: independent of FMA block
        const float* xf = &cur.x;
#pragma unroll
        for (int kk = 0; kk < 4; kk++) {
            float xs = xf[kk];
            const float4* wrow = &wlds[(k4 * 4 + kk) * (HID / 4)];  // wave-uniform ds_read (broadcast)
#pragma unroll
            for (int hq = 0; hq < HID / 4; hq++) {
                float4 wq = wrow[hq];
                acc[hq * 4 + 0] = fmaf(xs, wq.x, acc[hq * 4 + 0]);
                acc[hq * 4 + 1] = fmaf(xs, wq.y, acc[hq * 4 + 1]);
                acc[hq * 4 + 2] = fmaf(xs, wq.z, acc[hq * 4 + 2]);
                acc[hq * 4 + 3] = fmaf(xs, wq.w, acc[hq * 4 + 3]);
            }
        }
        cur = nxt;
    }

    if (!act) return;
    float4* __restrict__ ho = reinterpret_cast<float4*>(h + (size_t)n * HID);
    float p = 0.0f, q = 0.0f;
#pragma unroll
    for (int hq = 0; hq < HID / 4; hq++) {
        float4 v;
        v.x = fmaxf(acc[hq * 4 + 0], 0.0f);
        v.y = fmaxf(acc[hq * 4 + 1], 0.0f);
        v.z = fmaxf(acc[hq * 4 + 2], 0.0f);
        v.w = fmaxf(acc[hq * 4 + 3], 0.0f);
        ho[hq] = v;
        p = fmaf(v.x, att_l0[hq * 4 + 0], p); q = fmaf(v.x, att_r0[hq * 4 + 0], q);
        p = fmaf(v.y, att_l0[hq * 4 + 1], p); q = fmaf(v.y, att_r0[hq * 4 + 1], q);
        p = fmaf(v.z, att_l0[hq * 4 + 2], p); q = fmaf(v.z, att_r0[hq * 4 + 2], q);
        p = fmaf(v.w, att_l0[hq * 4 + 3], p); q = fmaf(v.w, att_r0[hq * 4 + 3], q);
    }
    float ds = dis[n];
    aldis[n] = make_float2(p, ds);
    ardis[n] = make_float2(q, ds);
}

// wave per node i. Lane split: g = lane>>4 (edge subgroup 0..3), f = lane&15 (float4 feature chunk).
// One dwordx4 load serves 4 edges at once; ds_bpermute with per-lane index t+g broadcasts
// 4 edges' {src, coef} in one instr. 2-deep pipeline (8 edges/iter, 2 accumulators).
// coef computed per-lane at preload (tanh fused); dst == i so ar_i/dis_i are wave-uniform.
// MODE 1: write h_out + next-layer scores into aldis_o/ardis_o (separate buffers).
// MODE 2: fused logits + log_softmax, no h_out.
template <int MODE>
__global__ __launch_bounds__(256) void k_agg(const float* __restrict__ h_in, const float* __restrict__ raw,
                                             const int* __restrict__ rp, const int* __restrict__ csr_src,
                                             const float2* __restrict__ aldis_i, const float2* __restrict__ ardis_i,
                                             float* __restrict__ h_out,
                                             const float* __restrict__ att_l, const float* __restrict__ att_r,
                                             const float* __restrict__ dis,
                                             float2* __restrict__ aldis_o, float2* __restrict__ ardis_o,
                                             const float* __restrict__ w2, const float* __restrict__ b2,
                                             float* __restrict__ out) {
    int lane = threadIdx.x & 63;
    int g = lane >> 4;       // edge subgroup
    int f = lane & 15;       // feature chunk (float4)
    int i = blockIdx.x * 4 + (threadIdx.x >> 6);
    if (i >= NN) return;
    float2 ai = ardis_i[i];  // {ar_i, dis_i} wave-uniform
    int e0 = rp[i], e1 = rp[i + 1];
    int deg = e1 - e0;

    float4 accA = make_float4(0.f, 0.f, 0.f, 0.f);
    float4 accB = make_float4(0.f, 0.f, 0.f, 0.f);

    for (int base = 0; base < deg; base += 64) {
        int rem = deg - base; if (rem > 64) rem = 64;
        int j = 0; float cf = 0.0f;
        if (lane < rem) {
            j = csr_src[e0 + base + lane];           // coalesced 4B
            float2 aj = aldis_i[j];                  // random 8B gather, 64 in flight
            cf = tanhf(aj.x + ai.x) * (aj.y * ai.y); // fused coef
        }
        for (int t = 0; t < rem; t += 8) {
            int i0 = t + g;
            int i1 = t + 4 + g;
            int s0 = i0 < rem ? i0 : rem - 1;        // clamp for shfl
            int s1 = i1 < rem ? i1 : rem - 1;
            int j0 = __shfl(j, s0, 64);
            int j1 = __shfl(j, s1, 64);
            float c0 = __shfl(cf, s0, 64);
            float c1 = __shfl(cf, s1, 64);
            if (i0 >= rem) c0 = 0.0f;                // padded edges contribute 0
            if (i1 >= rem) c1 = 0.0f;
            float4 h0 = *reinterpret_cast<const float4*>(h_in + j0 * HID + 4 * f);
            float4 h1 = *reinterpret_cast<const float4*>(h_in + j1 * HID + 4 * f);
            accA.x = fmaf(h0.x, c0, accA.x);
            accA.y = fmaf(h0.y, c0, accA.y);
            accA.z = fmaf(h0.z, c0, accA.z);
            accA.w = fmaf(h0.w, c0, accA.w);
            accB.x = fmaf(h1.x, c1, accB.x);
            accB.y = fmaf(h1.y, c1, accB.y);
            accB.z = fmaf(h1.z, c1, accB.z);
            accB.w = fmaf(h1.w, c1, accB.w);
        }
    }
    float4 acc;
    acc.x = accA.x + accB.x;
    acc.y = accA.y + accB.y;
    acc.z = accA.z + accB.z;
    acc.w = accA.w + accB.w;
    // reduce across the 4 edge subgroups -> all lanes hold full sums for their chunk
#pragma unroll
    for (int m = 16; m <= 32; m <<= 1) {
        acc.x += __shfl_xor(acc.x, m, 64);
        acc.y += __shfl_xor(acc.y, m, 64);
        acc.z += __shfl_xor(acc.z, m, 64);
        acc.w += __shfl_xor(acc.w, m, 64);
    }
    float4 rawv = *reinterpret_cast<const float4*>(raw + (size_t)i * HID + 4 * f);
    acc.x = fmaf(EPSF, rawv.x, acc.x);
    acc.y = fmaf(EPSF, rawv.y, acc.y);
    acc.z = fmaf(EPSF, rawv.z, acc.z);
    acc.w = fmaf(EPSF, rawv.w, acc.w);

    if (MODE == 2) {
        float lg[NCLS];
#pragma unroll
        for (int cc = 0; cc < NCLS; cc++) {
            float4 wv = *reinterpret_cast<const float4*>(w2 + cc * HID + 4 * f);
            float p = acc.x * wv.x + acc.y * wv.y + acc.z * wv.z + acc.w * wv.w;
#pragma unroll
            for (int m = 1; m < 16; m <<= 1) p += __shfl_xor(p, m, 64);
            lg[cc] = p + b2[cc];
        }
        float mx = lg[0];
#pragma unroll
        for (int cc = 1; cc < NCLS; cc++) mx = fmaxf(mx, lg[cc]);
        float ssum = 0.0f;
#pragma unroll
        for (int cc = 0; cc < NCLS; cc++) ssum += expf(lg[cc] - mx);
        float r = mx + logf(ssum);
        if (lane < NCLS) {
            float v = 0.0f;
#pragma unroll
            for (int cc = 0; cc < NCLS; cc++)
                if (lane == cc) v = lg[cc];
            out[(size_t)i * NCLS + lane] = v - r;
        }
    } else {
        if (g == 0) *reinterpret_cast<float4*>(h_out + (size_t)i * HID + 4 * f) = acc;
        if (MODE == 1) {
            float4 alv = *reinterpret_cast<const float4*>(att_l + 4 * f);
            float4 arv = *reinterpret_cast<const float4*>(att_r + 4 * f);
            float p = acc.x * alv.x + acc.y * alv.y + acc.z * alv.z + acc.w * alv.w;
            float q = acc.x * arv.x + acc.y * arv.y + acc.z * arv.z + acc.w * arv.w;
#pragma unroll
            for (int m = 1; m < 16; m <<= 1) {
                p += __shfl_xor(p, m, 64);
                q += __shfl_xor(q, m, 64);
            }
            if (lane == 0) {
                float ds = dis[i];
                aldis_o[i] = make_float2(p, ds);
                ardis_o[i] = make_float2(q, ds);
            }
        }
    }
}

// ---------- launch ----------

extern "C" void kernel_launch(void* const* d_in, const int* in_sizes, int n_in,
                              void* d_out, int out_size, void* d_ws, size_t ws_size,
                              hipStream_t stream) {
    const float* x     = (const float*)d_in[0];
    const int*   ei    = (const int*)d_in[1];
    const float* w1    = (const float*)d_in[2];
    const float* b1    = (const float*)d_in[3];
    const float* w2    = (const float*)d_in[4];
    const float* b2    = (const float*)d_in[5];
    const float* att_l = (const float*)d_in[6];
    const float* att_r = (const float*)d_in[7];
    float* out = (float*)d_out;

    char* ws = (char*)d_ws;
    size_t off = 0;
    auto take = [&](size_t bytes) -> void* {
        void* p = ws + off;
        off += (bytes + 255) & ~(size_t)255;
        return p;
    };
    int*    deg     = (int*)take((size_t)NN * 4);
    int*    cursor  = (int*)take((size_t)NN * 4);
    int*    rp      = (int*)take((size_t)(NN + 1) * 4);
    int*    bsum    = (int*)take(128 * 4);
    float*  dis     = (float*)take((size_t)NN * 4);
    float2* aldisA  = (float2*)take((size_t)NN * 8);
    float2* ardisA  = (float2*)take((size_t)NN * 8);
    float2* aldisB  = (float2*)take((size_t)NN * 8);
    float2* ardisB  = (float2*)take((size_t)NN * 8);
    float*  w1T     = (float*)take((size_t)HID * FIN * 4);
    int*    csr_src = (int*)take((size_t)NE * 4);
    float*  hA      = (float*)take((size_t)NN * HID * 4);
    float*  hB      = (float*)take((size_t)NN * HID * 4);

    hipMemsetAsync(deg, 0, (size_t)NN * 4, stream);
    hipMemsetAsync(cursor, 0, (size_t)NN * 4, stream);

    const int EB = (NE + 255) / 256;
    const int NB = (NN + 255) / 256;
    const int SB = (NN + 1023) / 1024;  // 98

    k_wt<<<64, 256, 0, stream>>>(w1, w1T);
    k_deg<<<EB, 256, 0, stream>>>(ei, deg);
    k_dis<<<NB, 256, 0, stream>>>(deg, dis);
    k_scan1<<<SB, 1024, 0, stream>>>(deg, rp, bsum);
    k_scan2<<<1, 128, 0, stream>>>(bsum, SB);
    k_scan3<<<SB, 1024, 0, stream>>>(rp, bsum);
    k_fill<<<EB, 256, 0, stream>>>(ei, rp, cursor, csr_src);

    // lin1 + ReLU + fused layer-0 scores -> aldisA/ardisA
    k_gemm1<<<(NN + 255) / 256, 256, 0, stream>>>(x, w1T, b1, dis, att_l, att_r, hA, aldisA, ardisA);

    // layer 0: in hA (scores A), raw hA -> hB, fused layer-1 scores -> B buffers
    k_agg<1><<<NN / 4, 256, 0, stream>>>(hA, hA, rp, csr_src, aldisA, ardisA, hB,
                                         att_l + HID, att_r + HID, dis, aldisB, ardisB,
                                         nullptr, nullptr, nullptr);

    // layer 1: in hB (scores B), raw hA -> fused logits/log_softmax -> out
    k_agg<2><<<NN / 4, 256, 0, stream>>>(hB, hA, rp, csr_src, aldisB, ardisB, nullptr,
                                         nullptr, nullptr, nullptr, nullptr, nullptr,
                                         w2, b2, out);
}